// Round 8
// baseline (2914.460 us; speedup 1.0000x reference)
//
#include <hip/hip_runtime.h>
#include <stdint.h>

// StackedRNN depth-3, B=16, T=2048, H=256. Inputs fp32, output fp32.
// Round 8: register-resident inp B-fragments via a global "fragment image"
// in d_ws.  Model (fits R1-R7): per-SIMD MFMA issue floor ~1242 cyc/step is
// fixed; the win is overlap.  In R3 all 16 B-frags came from LDS after the
// barrier (post-barrier ds_read gates the MFMA stream; 128KB/step redundant
// LDS reads).  Now: the inp half (kt 0-7, >=16-step slack) is PREPACKED in
// global as the exact per-frag lane image (8KB/step):
//   - stage 0's image: written by a 4th transposer WG from x (pkrtz bits
//     identical to the old loader),
//   - stage k>0's image: upstream serial WG mirrors its hpk uint2s (same
//     bits the old path re-packed from out).
// Consumers load 8 coalesced dwordx4/wave ONE STEP AHEAD into registers:
// step t opens with 8 MFMAs on register operands (no LDS dependency) while
// the 8 h-frag ds_reads fly.  LDS/step: 128KB+24 -> 64KB+4.
// Accumulation order bias -> inp kt0..7 -> h kt8..15 preserved exactly =>
// absmax canary must stay 0.00390625.
// Flag protocol/cadence byte-identical to verified R3 (publish every 8
// backed by full __syncthreads at (t&7)==7, gates every 16, light barrier
// with no vmcnt drain on 7/8 steps).  R4 lesson respected: all cross-WG
// reads keep >=16-step slack.
// Fallback: if ws_size < 48MB+4KB, launch the verified R3 kernel (2133us).

#define TT 2048
#define HH 256

typedef _Float16 h16x8 __attribute__((ext_vector_type(8)));
typedef float f32x4 __attribute__((ext_vector_type(4)));

__device__ __forceinline__ unsigned pkrtz(float a, float b) {
  return __builtin_bit_cast(unsigned, __builtin_amdgcn_cvt_pkrtz(a, b));
}

__device__ __forceinline__ uint4 pack8u(float4 a, float4 b) {
  return make_uint4(pkrtz(a.x, a.y), pkrtz(a.z, a.w),
                    pkrtz(b.x, b.y), pkrtz(b.z, b.w));
}

// tanh(x) = 1 - 2e/(1+e), e = e^{-2x} = exp2(-2*log2(e)*x).  ~1e-6 err.
__device__ __forceinline__ float tanh_fast(float x) {
  float xm = fmaxf(x, -15.0f);
  float e = __builtin_amdgcn_exp2f(xm * -2.88539008177793f);
  float r = __builtin_amdgcn_rcpf(1.0f + e);
  return __builtin_fmaf(-2.0f * e, r, 1.0f);
}

__device__ __forceinline__ void spin_ge(int* p, int need) {
  while (__hip_atomic_load(p, __ATOMIC_ACQUIRE, __HIP_MEMORY_SCOPE_AGENT) < need)
    __builtin_amdgcn_s_sleep(2);
}

__device__ __forceinline__ void light_barrier() {
  asm volatile("s_waitcnt expcnt(0) lgkmcnt(0)" ::: "memory");
  __builtin_amdgcn_s_barrier();
}

// ============================ new kernel =================================
// Fragment image (per stage, per step: 8KB): frag j (k in [32j,32j+32)) at
// byte j*1024; lane l=(q*16+n) reads 16B at l*16 = halves k=32j+8q..+8,
// batch n.  Image t at base + t*8192; stage s base = flags+4096 + s*16MB.
// H panel LDS (fp16, K=256): granule u=k>>3, half-index
// (u*16 + (n^(u&7)))*8 + (k&7); frag jk at rd{E,O} + jk*512.
__global__ __launch_bounds__(512, 2)
void stacked_rnn_img(const float* __restrict__ x,
                     const int* __restrict__ seq_lens,
                     const float* __restrict__ Wih,
                     const float* __restrict__ Whh,
                     const float* __restrict__ bias,
                     float* __restrict__ out,
                     int* flags) {
  const int bid = (int)blockIdx.x;
  const int tid = (int)threadIdx.x;
  char* const img_all = (char*)flags + 4096;

  if (bid == 3) {
    // ---------------- transposer: x -> stage-0 fragment image -------------
    const int n_l = tid >> 5;
    const int k8  = tid & 31;
    const float* sx = x + n_l * (TT * HH) + (k8 << 3);
    char* dst = img_all + ((k8 >> 2) * 1024 + (((k8 & 3) * 16) + n_l) * 16);
    int* fMe = flags + 3 * 64;
    for (int c = 0; c < TT; c += 16) {
#pragma unroll 4
      for (int tt = 0; tt < 16; ++tt) {
        const float* sp = sx + (c + tt) * HH;
        float4 a = ((const float4*)sp)[0];
        float4 b = ((const float4*)sp)[1];
        *(uint4*)(dst + (size_t)(c + tt) * 8192) = pack8u(a, b);
      }
      __syncthreads();   // drains all threads' image stores
      if (tid == 0)
        __hip_atomic_store(fMe, c + 16, __ATOMIC_RELEASE,
                           __HIP_MEMORY_SCOPE_AGENT);
    }
    return;
  }

  // ---------------- serial stage ks ---------------------------------------
  const int ks = bid;
  const int w = tid >> 6;              // wave 0..7 -> rows [32w, 32w+32)
  const int lane = tid & 63;
  const int q = lane >> 4;
  const int n = lane & 15;

  __shared__ __align__(16) unsigned short Hsm[2][4096];  // 2 x 8KB h panels

  int* flag_me = flags + ks * 64;
  int* flag_up = flags + ((ks == 0) ? 3 : (ks - 1)) * 64;
  const char* img_rd = img_all + (size_t)ks * TT * 8192;
  char* img_wr = img_all + (size_t)((ks < 2) ? (ks + 1) : 2) * TT * 8192;

  // ---- weights (fp16 RNE, R3-identical): kt<8 = W_ih, kt>=8 = W_hh
  h16x8 wf[2][16];
  {
    const float* wih_s = Wih + ks * (HH * HH);
    const float* whh_s = Whh + ks * (HH * HH);
#pragma unroll
    for (int mti = 0; mti < 2; ++mti) {
      const int fA = w * 32 + mti * 16 + n;
#pragma unroll
      for (int kt = 0; kt < 16; ++kt) {
        const int col = (kt & 7) * 32 + q * 8;
        const float* src = (kt < 8) ? (wih_s + fA * HH + col)
                                    : (whh_s + fA * HH + col);
        float4 a0 = ((const float4*)src)[0];
        float4 a1 = ((const float4*)src)[1];
        h16x8 f;
        f[0] = (_Float16)a0.x; f[1] = (_Float16)a0.y;
        f[2] = (_Float16)a0.z; f[3] = (_Float16)a0.w;
        f[4] = (_Float16)a1.x; f[5] = (_Float16)a1.y;
        f[6] = (_Float16)a1.z; f[7] = (_Float16)a1.w;
        wf[mti][kt] = f;
      }
    }
  }

  f32x4 biasv[2];
#pragma unroll
  for (int mti = 0; mti < 2; ++mti)
#pragma unroll
    for (int r = 0; r < 4; ++r)
      biasv[mti][r] = bias[ks * HH + w * 32 + mti * 16 + q * 4 + r];

  const int sl = seq_lens[n];

  const int rdE = (q * 16 + (n ^ q)) * 8;
  const int rdO = (q * 16 + (n ^ q ^ 4)) * 8;
  int hofs[2], mofs[2];
#pragma unroll
  for (int mti = 0; mti < 2; ++mti) {
    const int u = w * 4 + mti * 2 + (q >> 1);
    hofs[mti] = (u * 16 + (n ^ (u & 7))) * 8 + (q & 1) * 4;
    mofs[mti] = w * 1024 + ((mti * 2 + (q >> 1)) * 16 + n) * 16 + (q & 1) * 8;
  }

  // ---- prologue: zero h buf0; gate (flag >= 17 covers images 0..16)
  ((uint4*)&Hsm[0][0])[tid] = make_uint4(0, 0, 0, 0);
  if (tid == 0) spin_ge(flag_up, 17);
  __syncthreads();

  uint4 ifr[8];   // inp_t B-frags (register-resident, refilled each step)
#pragma unroll
  for (int j = 0; j < 8; ++j)
    ifr[j] = *(const uint4*)(img_rd + j * 1024 + (lane << 4));
  const char* ird = img_rd + 8192;     // image of step t+1

  float* outp = out + (n * (TT * 3) + ks) * HH + w * 32 + q * 4;
  char* mwp = img_wr;                  // mirror write, advances 8KB/step

  for (int t = 0; t < TT; ++t) {
    const unsigned short* Hp = Hsm[t & 1];
    unsigned short* Hq = Hsm[(t & 1) ^ 1];

    // ---- publish (stores+mirrors drained by full barrier of iter t-1)
    if ((t & 7) == 0 && t > 0 && ks < 2 && tid == 0)
      __hip_atomic_store(flag_me, t, __ATOMIC_RELEASE,
                         __HIP_MEMORY_SCOPE_AGENT);
    // ---- gate: iters t..t+15 load images up to step t+16 -> need t+17
    if ((t & 15) == 0 && t > 0) {
      if (tid == 0) {
        int need = t + 17;
        if (need > TT) need = TT;
        spin_ge(flag_up, need);
      }
      __syncthreads();
    }

    // ---- GEMM: acc = bias + W_ih @ inp_t (regs) + W_hh @ h_{t-1} (LDS)
    f32x4 acc[2] = {biasv[0], biasv[1]};
#pragma unroll
    for (int kt = 0; kt < 8; ++kt) {
      h16x8 bf = __builtin_bit_cast(h16x8, ifr[kt]);
      acc[0] = __builtin_amdgcn_mfma_f32_16x16x32_f16(wf[0][kt], bf, acc[0], 0, 0, 0);
      acc[1] = __builtin_amdgcn_mfma_f32_16x16x32_f16(wf[1][kt], bf, acc[1], 0, 0, 0);
    }
#pragma unroll
    for (int kt = 0; kt < 8; ++kt) {
      h16x8 hf = *(const h16x8*)&Hp[((kt & 1) ? rdO : rdE) + kt * 512];
      acc[0] = __builtin_amdgcn_mfma_f32_16x16x32_f16(wf[0][8 + kt], hf, acc[0], 0, 0, 0);
      acc[1] = __builtin_amdgcn_mfma_f32_16x16x32_f16(wf[1][8 + kt], hf, acc[1], 0, 0, 0);
    }

    // ---- issue image loads for inp_{t+1} (consumed next step; in flight
    //      across the light barrier — no vmcnt drain)
    if (t + 1 < TT) {
#pragma unroll
      for (int j = 0; j < 8; ++j)
        ifr[j] = *(const uint4*)(ird + j * 1024 + (lane << 4));
    }
    ird += 8192;

    // ---- tanh + masked out-store + mirror store + h -> LDS pong
    const bool live = (t < sl);
    const bool wr = (t + 1 < TT);
    uint2 hpk[2];
#pragma unroll
    for (int mti = 0; mti < 2; ++mti) {
      float h0 = tanh_fast(acc[mti][0]);
      float h1 = tanh_fast(acc[mti][1]);
      float h2 = tanh_fast(acc[mti][2]);
      float h3 = tanh_fast(acc[mti][3]);
      hpk[mti].x = pkrtz(h0, h1);
      hpk[mti].y = pkrtz(h2, h3);
      float4 od;
      od.x = live ? h0 : 0.0f;
      od.y = live ? h1 : 0.0f;
      od.z = live ? h2 : 0.0f;
      od.w = live ? h3 : 0.0f;
      *(float4*)(outp + mti * 16) = od;                 // fire-and-forget
      if (ks < 2) *(uint2*)(mwp + mofs[mti]) = hpk[mti]; // downstream image
      if (wr) *(uint2*)&Hq[hofs[mti]] = hpk[mti];
    }
    outp += 3 * HH;
    mwp += 8192;

    // ---- barrier: light except every 8th (backs the publish)
    if ((t & 7) == 7) {
      __syncthreads();
    } else {
      light_barrier();
    }
  }

  if (ks < 2 && tid == 0)
    __hip_atomic_store(flag_me, TT, __ATOMIC_RELEASE, __HIP_MEMORY_SCOPE_AGENT);
}

// ===================== fallback: verified R3 kernel (2133us) =============
__global__ __launch_bounds__(512, 2)
void stacked_rnn_v3(const float* __restrict__ x,
                    const int* __restrict__ seq_lens,
                    const float* __restrict__ Wih,
                    const float* __restrict__ Whh,
                    const float* __restrict__ bias,
                    float* __restrict__ out,
                    int* flags) {
  const int ks = blockIdx.x;
  const int tid = (int)threadIdx.x;
  const int w = tid >> 6;
  const int lane = tid & 63;
  const int q = lane >> 4;
  const int n = lane & 15;

  __shared__ __align__(16) unsigned short Bsm[2][8192];

  int* flag_up = flags + (ks - 1) * 64;
  int* flag_me = flags + ks * 64;

  h16x8 wf[2][16];
  {
    const float* wih_s = Wih + ks * (HH * HH);
    const float* whh_s = Whh + ks * (HH * HH);
#pragma unroll
    for (int mti = 0; mti < 2; ++mti) {
      const int fA = w * 32 + mti * 16 + n;
#pragma unroll
      for (int kt = 0; kt < 16; ++kt) {
        const int col = (kt & 7) * 32 + q * 8;
        const float* src = (kt < 8) ? (wih_s + fA * HH + col)
                                    : (whh_s + fA * HH + col);
        float4 a0 = ((const float4*)src)[0];
        float4 a1 = ((const float4*)src)[1];
        h16x8 f;
        f[0] = (_Float16)a0.x; f[1] = (_Float16)a0.y;
        f[2] = (_Float16)a0.z; f[3] = (_Float16)a0.w;
        f[4] = (_Float16)a1.x; f[5] = (_Float16)a1.y;
        f[6] = (_Float16)a1.z; f[7] = (_Float16)a1.w;
        wf[mti][kt] = f;
      }
    }
  }

  f32x4 biasv[2];
#pragma unroll
  for (int mti = 0; mti < 2; ++mti)
#pragma unroll
    for (int r = 0; r < 4; ++r)
      biasv[mti][r] = bias[ks * HH + w * 32 + mti * 16 + q * 4 + r];

  const int sl = seq_lens[n];
  const int rdE = (q * 16 + (n ^ q)) * 8;
  const int rdO = (q * 16 + (n ^ q ^ 4)) * 8;
  int hofs[2];
#pragma unroll
  for (int mti = 0; mti < 2; ++mti) {
    const int u = (8 + w) * 4 + mti * 2 + (q >> 1);
    hofs[mti] = (u * 16 + (n ^ (u & 7))) * 8 + (q & 1) * 4;
  }

  const int n_l = tid >> 5;
  const int k8  = tid & 31;
  const int u_l = (k8 >> 2) * 4 + (k8 & 3);
  const int ldst = (u_l * 16 + (n_l ^ (u_l & 7))) * 8;

  const float* src_base;
  int src_stride;
  if (ks == 0) {
    src_base = x + ((n_l * TT) << 8) + (k8 << 3);
    src_stride = HH;
  } else {
    src_base = out + (((n_l * TT) * 3 + (ks - 1)) << 8) + (k8 << 3);
    src_stride = 3 * HH;
  }

  ((uint4*)&Bsm[0][4096])[tid] = make_uint4(0, 0, 0, 0);
  if (ks > 0 && tid == 0) spin_ge(flag_up, 18);
  __syncthreads();

  {
    float4 c0 = ((const float4*)src_base)[0];
    float4 c1 = ((const float4*)src_base)[1];
    *(uint4*)&Bsm[0][ldst] = pack8u(c0, c1);
  }
  float4 pfB0 = ((const float4*)(src_base + src_stride))[0];
  float4 pfB1 = ((const float4*)(src_base + src_stride))[1];
  const float* src_pf = src_base + 2 * src_stride;
  __syncthreads();

  float* outp = out + ((n * TT) * 3 + ks) * HH + w * 32 + q * 4;

  for (int t = 0; t < TT; ++t) {
    unsigned short* Bp = Bsm[t & 1];
    unsigned short* Bq = Bsm[(t & 1) ^ 1];

    if ((t & 7) == 0 && t > 0 && ks < 2 && tid == 0)
      __hip_atomic_store(flag_me, t, __ATOMIC_RELEASE,
                         __HIP_MEMORY_SCOPE_AGENT);
    if ((t & 15) == 0 && t > 0 && ks > 0) {
      if (tid == 0) {
        int need = t + 18;
        if (need > TT) need = TT;
        spin_ge(flag_up, need);
      }
      __syncthreads();
    }

    float4 pfA0, pfA1;
    const bool more2 = (t + 2 < TT);
    if (more2) {
      pfA0 = ((const float4*)src_pf)[0];
      pfA1 = ((const float4*)src_pf)[1];
    }
    src_pf += src_stride;

    f32x4 acc[2] = {biasv[0], biasv[1]};
#pragma unroll
    for (int kt = 0; kt < 16; ++kt) {
      const int ofs = ((kt & 1) ? rdO : rdE) + kt * 512;
      h16x8 bf = *(const h16x8*)&Bp[ofs];
      acc[0] = __builtin_amdgcn_mfma_f32_16x16x32_f16(wf[0][kt], bf, acc[0], 0, 0, 0);
      acc[1] = __builtin_amdgcn_mfma_f32_16x16x32_f16(wf[1][kt], bf, acc[1], 0, 0, 0);
    }

    const bool live = (t < sl);
    uint2 hpk[2];
#pragma unroll
    for (int mti = 0; mti < 2; ++mti) {
      float h0 = tanh_fast(acc[mti][0]);
      float h1 = tanh_fast(acc[mti][1]);
      float h2 = tanh_fast(acc[mti][2]);
      float h3 = tanh_fast(acc[mti][3]);
      hpk[mti].x = pkrtz(h0, h1);
      hpk[mti].y = pkrtz(h2, h3);
      float4 od;
      od.x = live ? h0 : 0.0f;
      od.y = live ? h1 : 0.0f;
      od.z = live ? h2 : 0.0f;
      od.w = live ? h3 : 0.0f;
      *(float4*)(outp + mti * 16) = od;
    }
    outp += 3 * HH;

    if (t + 1 < TT) {
      *(uint4*)&Bq[ldst] = pack8u(pfB0, pfB1);
      *(uint2*)&Bq[hofs[0]] = hpk[0];
      *(uint2*)&Bq[hofs[1]] = hpk[1];
      if (more2) { pfB0 = pfA0; pfB1 = pfA1; }
    }

    if ((t & 7) == 7) {
      __syncthreads();
    } else {
      light_barrier();
    }
  }

  if (ks < 2 && tid == 0)
    __hip_atomic_store(flag_me, TT, __ATOMIC_RELEASE, __HIP_MEMORY_SCOPE_AGENT);
}

extern "C" void kernel_launch(void* const* d_in, const int* in_sizes, int n_in,
                              void* d_out, int out_size, void* d_ws, size_t ws_size,
                              hipStream_t stream) {
  (void)in_sizes; (void)n_in; (void)out_size;
  const float* x   = (const float*)d_in[0];
  const int*   sl  = (const int*)d_in[1];
  const float* wih = (const float*)d_in[2];
  const float* whh = (const float*)d_in[3];
  const float* b   = (const float*)d_in[4];

  (void)hipMemsetAsync(d_ws, 0, 4096, stream);
  const size_t need = 4096 + (size_t)3 * TT * 8192;   // flags + 3 images
  if (ws_size >= need) {
    hipLaunchKernelGGL(stacked_rnn_img, dim3(4), dim3(512), 0, stream,
                       x, sl, wih, whh, b, (float*)d_out, (int*)d_ws);
  } else {
    hipLaunchKernelGGL(stacked_rnn_v3, dim3(3), dim3(512), 0, stream,
                       x, sl, wih, whh, b, (float*)d_out, (int*)d_ws);
  }
}

// Round 9
// 2413.917 us; speedup vs baseline: 1.2074x; 1.2074x over previous
//
#include <hip/hip_runtime.h>
#include <stdint.h>

// StackedRNN depth-3, B=16, T=2048, H=256. Inputs fp32, output fp32.
// Round 9: TAIL-FILLED SOFTWARE PIPELINE, all in-WG (R4/R8 lesson: per-step
// data must stay local).  3 persistent WGs, 512 threads (8 waves, 2/SIMD).
// Key idea: the inp-half of step t+1's GEMM has no h-dependency and its
// panel is already in LDS -- so compute it in step t's TAIL, where the
// MFMA pipe was idle behind tanh/pack/stores:
//   step t: [8 h-MFMAs into carried accC] -> tanh/store ->
//           [8 inp-MFMAs from reg-frags -> accC for t+1] -> writes -> barrier
// Per-step critical path drops from 16 MFMAs+full tail to 8 MFMAs+tanh;
// MFMA issue floor (~1242 cyc/step/SIMD) stays fed through the tail.
// inp frags for t+1 are ds_read into registers during t (ifr, 32 VGPR).
// Panels: H[2] (h ping-pong) + I[2] (inp ping-pong: write inp_{t+2} into
// I[t&1], read inp_{t+1} from I[(t+1)&1] -- disjoint every step), both
// XOR-swizzled K=256 layout (R4-serial / R7 verified formulas).
// Numerics: accumulation order bias -> inp kt0..7 -> h kt0..7 identical to
// R3 => bit-identical output (absmax canary 0.00390625).
// Sync: R3's verified cadence (light barrier 7/8 steps, full __syncthreads
// at (t&7)==7 backing the 8-step publish; gate every 16, need t+19 as R7).

#define TT 2048
#define HH 256

typedef _Float16 h16x8 __attribute__((ext_vector_type(8)));
typedef float f32x4 __attribute__((ext_vector_type(4)));

__device__ __forceinline__ unsigned pkrtz(float a, float b) {
  return __builtin_bit_cast(unsigned, __builtin_amdgcn_cvt_pkrtz(a, b));
}

// pack 8 fp32 -> 8 fp16 halves (RTZ pair-pack, identical bits to baseline)
__device__ __forceinline__ uint4 pack8u(float4 a, float4 b) {
  return make_uint4(pkrtz(a.x, a.y), pkrtz(a.z, a.w),
                    pkrtz(b.x, b.y), pkrtz(b.z, b.w));
}

// tanh(x) = 1 - 2e/(1+e), e = e^{-2x} = exp2(-2*log2(e)*x).  ~1e-6 err.
__device__ __forceinline__ float tanh_fast(float x) {
  float xm = fmaxf(x, -15.0f);
  float e = __builtin_amdgcn_exp2f(xm * -2.88539008177793f);
  float r = __builtin_amdgcn_rcpf(1.0f + e);
  return __builtin_fmaf(-2.0f * e, r, 1.0f);
}

__device__ __forceinline__ void spin_ge(int* p, int need) {
  while (__hip_atomic_load(p, __ATOMIC_ACQUIRE, __HIP_MEMORY_SCOPE_AGENT) < need)
    __builtin_amdgcn_s_sleep(2);
}

// Light barrier: order LDS ops (lgkmcnt) + store-data reads (expcnt) but
// leave global loads/stores in flight (T4: no vmcnt drain in the loop).
__device__ __forceinline__ void light_barrier() {
  asm volatile("s_waitcnt expcnt(0) lgkmcnt(0)" ::: "memory");
  __builtin_amdgcn_s_barrier();
}

// Panel layout (fp16, K=256): granule(16B) for (k,n): u = k>>3,
//   half-index = (u*16 + (n ^ (u&7)))*8 + (k&7).
// Frag kt (lane q,n) at rd{E,O} + kt*512:  rdE (even kt, u&7=q),
//   rdO (odd kt, u&7=q^4).  Verified in R4-serial/R7.
__global__ __launch_bounds__(512, 2)
void stacked_rnn(const float* __restrict__ x,
                 const int* __restrict__ seq_lens,
                 const float* __restrict__ Wih,
                 const float* __restrict__ Whh,
                 const float* __restrict__ bias,
                 float* __restrict__ out,
                 int* flags) {
  const int ks = blockIdx.x;           // depth stage 0..2
  const int tid = (int)threadIdx.x;
  const int w = tid >> 6;              // wave 0..7 -> rows [32w, 32w+32)
  const int lane = tid & 63;
  const int q = lane >> 4;
  const int n = lane & 15;             // batch column

  __shared__ __align__(16) unsigned short Hsm[2][4096];  // 2 x 8KB h panels
  __shared__ __align__(16) unsigned short Ism[2][4096];  // 2 x 8KB inp panels

  int* flag_up = flags + (ks - 1) * 64;
  int* flag_me = flags + ks * 64;

  // ---- persistent weight A-fragments (fp16 RNE): kt<8 = W_ih, kt>=8 = W_hh
  h16x8 wf[2][16];
  {
    const float* wih_s = Wih + ks * (HH * HH);
    const float* whh_s = Whh + ks * (HH * HH);
#pragma unroll
    for (int mti = 0; mti < 2; ++mti) {
      const int fA = w * 32 + mti * 16 + n;      // A row = lane&15
#pragma unroll
      for (int kt = 0; kt < 16; ++kt) {
        const int col = (kt & 7) * 32 + q * 8;   // A k = quad*8 + j
        const float* src = (kt < 8) ? (wih_s + fA * HH + col)
                                    : (whh_s + fA * HH + col);
        float4 a0 = ((const float4*)src)[0];
        float4 a1 = ((const float4*)src)[1];
        h16x8 f;
        f[0] = (_Float16)a0.x; f[1] = (_Float16)a0.y;
        f[2] = (_Float16)a0.z; f[3] = (_Float16)a0.w;
        f[4] = (_Float16)a1.x; f[5] = (_Float16)a1.y;
        f[6] = (_Float16)a1.z; f[7] = (_Float16)a1.w;
        wf[mti][kt] = f;
      }
    }
  }

  // ---- bias in C-layout (row = q*4+r, col = n), exact fp32
  f32x4 biasv[2];
#pragma unroll
  for (int mti = 0; mti < 2; ++mti)
#pragma unroll
    for (int r = 0; r < 4; ++r)
      biasv[mti][r] = bias[ks * HH + w * 32 + mti * 16 + q * 4 + r];

  const int sl = seq_lens[n];

  // ---- frag read offsets (halves): frag kt at rd{E,O} + kt*512
  const int rdE = (q * 16 + (n ^ q)) * 8;        // even kt: u&7 = q
  const int rdO = (q * 16 + (n ^ q ^ 4)) * 8;    // odd  kt: u&7 = q^4

  // ---- h-repack write offsets (uint2 = 4 halves)
  int hofs[2];
#pragma unroll
  for (int mti = 0; mti < 2; ++mti) {
    const int u = w * 4 + mti * 2 + (q >> 1);
    hofs[mti] = (u * 16 + (n ^ (u & 7))) * 8 + (q & 1) * 4;
  }

  // ---- loader: 512 chunks of 8 floats = {n 0..15} x {k8 0..31}, 1/thread
  const int n_l = tid >> 5;
  const int k8  = tid & 31;
  const int ldstI = (k8 * 16 + (n_l ^ (k8 & 7))) * 8;   // u = k8 (K=256)

  const float* src_base;
  int src_stride;
  if (ks == 0) {
    src_base = x + ((n_l * TT) << 8) + (k8 << 3);
    src_stride = HH;
  } else {
    src_base = out + (((n_l * TT) * 3 + (ks - 1)) << 8) + (k8 << 3);
    src_stride = 3 * HH;
  }

  // ---- prologue: zero H[0] (h_{-1}=0); gate covers inp_0..18
  ((uint4*)&Hsm[0][0])[tid] = make_uint4(0, 0, 0, 0);
  if (ks > 0 && tid == 0) spin_ge(flag_up, 19);
  __syncthreads();

  // stage inp_0 -> I[0], inp_1 -> I[1]; raw inp_2 -> pfB; pf ptr at inp_3
  {
    float4 c0 = ((const float4*)src_base)[0];
    float4 c1 = ((const float4*)src_base)[1];
    *(uint4*)&Ism[0][ldstI] = pack8u(c0, c1);
    float4 d0 = ((const float4*)(src_base + src_stride))[0];
    float4 d1 = ((const float4*)(src_base + src_stride))[1];
    *(uint4*)&Ism[1][ldstI] = pack8u(d0, d1);
  }
  float4 pfB0 = ((const float4*)(src_base + 2 * src_stride))[0];
  float4 pfB1 = ((const float4*)(src_base + 2 * src_stride))[1];
  const float* src_pf = src_base + 3 * src_stride;
  __syncthreads();

  // accC = bias + W_ih @ inp_0  (priming the pipeline)
  f32x4 accC0 = biasv[0], accC1 = biasv[1];
#pragma unroll
  for (int kt = 0; kt < 8; ++kt) {
    h16x8 bf = *(const h16x8*)&Ism[0][((kt & 1) ? rdO : rdE) + kt * 512];
    accC0 = __builtin_amdgcn_mfma_f32_16x16x32_f16(wf[0][kt], bf, accC0, 0, 0, 0);
    accC1 = __builtin_amdgcn_mfma_f32_16x16x32_f16(wf[1][kt], bf, accC1, 0, 0, 0);
  }
  __syncthreads();   // prologue I[0] reads drained before t=0 overwrites it

  float* outp = out + (n * (TT * 3) + ks) * HH + w * 32 + q * 4;

  for (int t = 0; t < TT; ++t) {
    // ---- publish (stores drained by full barrier at end of iter t-1)
    if ((t & 7) == 0 && t > 0 && ks < 2 && tid == 0)
      __hip_atomic_store(flag_me, t, __ATOMIC_RELEASE,
                         __HIP_MEMORY_SCOPE_AGENT);
    // ---- gate: window t..t+15 loads raw inp up to t+18 -> need t+19
    if ((t & 15) == 0 && t > 0 && ks > 0) {
      if (tid == 0) {
        int need = t + 19;
        if (need > TT) need = TT;
        spin_ge(flag_up, need);
      }
      __syncthreads();
    }

    // ---- issue raw global prefetch for inp_{t+3}
    float4 pfA0, pfA1;
    const bool more3 = (t + 3 < TT);
    if (more3) {
      pfA0 = ((const float4*)src_pf)[0];
      pfA1 = ((const float4*)src_pf)[1];
    }
    src_pf += src_stride;

    // ---- critical half: accC += W_hh @ h_{t-1}  (8 MFMAs, post-barrier)
    const unsigned short* Hp = Hsm[t & 1];
#pragma unroll
    for (int kt = 0; kt < 8; ++kt) {
      h16x8 hf = *(const h16x8*)&Hp[((kt & 1) ? rdO : rdE) + kt * 512];
      accC0 = __builtin_amdgcn_mfma_f32_16x16x32_f16(wf[0][8 + kt], hf, accC0, 0, 0, 0);
      accC1 = __builtin_amdgcn_mfma_f32_16x16x32_f16(wf[1][8 + kt], hf, accC1, 0, 0, 0);
    }

    // ---- load inp_{t+1} frags into registers (panel visible since last
    //      barrier; consumed in this step's tail)
    const bool more1 = (t + 1 < TT);
    h16x8 ifr[8];
    if (more1) {
      const unsigned short* Ip = Ism[(t + 1) & 1];
#pragma unroll
      for (int kt = 0; kt < 8; ++kt)
        ifr[kt] = *(const h16x8*)&Ip[((kt & 1) ? rdO : rdE) + kt * 512];
    }

    // ---- tanh + masked fp32 output store (h kept unmasked for recurrence)
    const bool live = (t < sl);
    uint2 hpk[2];
    f32x4 acc[2] = {accC0, accC1};
#pragma unroll
    for (int mti = 0; mti < 2; ++mti) {
      float h0 = tanh_fast(acc[mti][0]);
      float h1 = tanh_fast(acc[mti][1]);
      float h2 = tanh_fast(acc[mti][2]);
      float h3 = tanh_fast(acc[mti][3]);
      hpk[mti].x = pkrtz(h0, h1);
      hpk[mti].y = pkrtz(h2, h3);
      float4 od;
      od.x = live ? h0 : 0.0f;
      od.y = live ? h1 : 0.0f;
      od.z = live ? h2 : 0.0f;
      od.w = live ? h3 : 0.0f;
      *(float4*)(outp + mti * 16) = od;
    }
    outp += 3 * HH;

    // ---- tail-filled pipeline: accC(next) = bias + W_ih @ inp_{t+1}
    //      (MFMA pipe otherwise idle behind tanh/stores; reg operands)
    if (more1) {
      f32x4 aN0 = biasv[0], aN1 = biasv[1];
#pragma unroll
      for (int kt = 0; kt < 8; ++kt) {
        aN0 = __builtin_amdgcn_mfma_f32_16x16x32_f16(wf[0][kt], ifr[kt], aN0, 0, 0, 0);
        aN1 = __builtin_amdgcn_mfma_f32_16x16x32_f16(wf[1][kt], ifr[kt], aN1, 0, 0, 0);
      }
      accC0 = aN0; accC1 = aN1;
    }

    // ---- LDS writes: h_t -> H pong, packed inp_{t+2} -> I[t&1]
    if (more1) {
      unsigned short* Hq = Hsm[(t & 1) ^ 1];
      *(uint2*)&Hq[hofs[0]] = hpk[0];
      *(uint2*)&Hq[hofs[1]] = hpk[1];
    }
    if (t + 2 < TT)
      *(uint4*)&Ism[t & 1][ldstI] = pack8u(pfB0, pfB1);
    if (more3) { pfB0 = pfA0; pfB1 = pfA1; }

    // ---- the one per-step barrier: light except every 8th (backs publish)
    if ((t & 7) == 7) {
      __syncthreads();
    } else {
      light_barrier();
    }
  }

  if (ks < 2 && tid == 0)
    __hip_atomic_store(flag_me, TT, __ATOMIC_RELEASE, __HIP_MEMORY_SCOPE_AGENT);
}

extern "C" void kernel_launch(void* const* d_in, const int* in_sizes, int n_in,
                              void* d_out, int out_size, void* d_ws, size_t ws_size,
                              hipStream_t stream) {
  (void)in_sizes; (void)n_in; (void)out_size; (void)ws_size;
  const float* x   = (const float*)d_in[0];
  const int*   sl  = (const int*)d_in[1];
  const float* wih = (const float*)d_in[2];
  const float* whh = (const float*)d_in[3];
  const float* b   = (const float*)d_in[4];

  // zero the progress flags (ws is poisoned 0xAA before every launch)
  (void)hipMemsetAsync(d_ws, 0, 1024, stream);
  hipLaunchKernelGGL(stacked_rnn, dim3(3), dim3(512), 0, stream,
                     x, sl, wih, whh, b, (float*)d_out, (int*)d_ws);
}

// Round 10
// 2239.775 us; speedup vs baseline: 1.3012x; 1.0777x over previous
//
#include <hip/hip_runtime.h>
#include <stdint.h>

// StackedRNN depth-3, B=16, T=2048, H=256. Inputs fp32, output fp32.
// 3 persistent workgroups (one per depth), 512 threads (8 waves, 2/SIMD).
// Weights fp16-resident in VGPRs (wf[2][16] = 128 VGPR/lane), batch=16 in
// MFMA N, depth pipelined through d_out with agent-scope progress flags.
// Single barrier/step (ping-pong LDS B), XOR-swizzled LDS (conflict-free),
// exp2-based tanh, 2-step-deep global prefetch. LIGHT per-step barrier
// (expcnt/lgkmcnt only, NO vmcnt drain) on 7 of 8 steps; full
// __syncthreads() at (t&7)==7 so the flag publish at t%8==0 has all
// threads' out-stores drained.
// SESSION VERDICT (R0-R9): this is the verified optimum of this structure
// (2133us). MFMA busy is invariant ~1.02 CU-ms across all variants; five
// structural attacks (fat waves, cross-WG split, wave specialization x2,
// global staging, tail-fill) each regressed 4-330% -- every loop-body
// reshape costs more in compiler-schedule quality than its mechanism
// gains. Remaining ~20% vs ideal-overlap arithmetic is schedule-bound.

#define TT 2048
#define HH 256

typedef _Float16 h16x8 __attribute__((ext_vector_type(8)));
typedef float f32x4 __attribute__((ext_vector_type(4)));

__device__ __forceinline__ unsigned pkrtz(float a, float b) {
  return __builtin_bit_cast(unsigned, __builtin_amdgcn_cvt_pkrtz(a, b));
}

// tanh(x) = 1 - 2e/(1+e), e = e^{-2x} = exp2(-2*log2(e)*x).  ~1e-6 err.
// clamp low side so e stays finite (avoids inf*0 NaN).
__device__ __forceinline__ float tanh_fast(float x) {
  float xm = fmaxf(x, -15.0f);
  float e = __builtin_amdgcn_exp2f(xm * -2.88539008177793f);
  float r = __builtin_amdgcn_rcpf(1.0f + e);
  return __builtin_fmaf(-2.0f * e, r, 1.0f);
}

__device__ __forceinline__ void spin_ge(int* p, int need) {
  while (__hip_atomic_load(p, __ATOMIC_ACQUIRE, __HIP_MEMORY_SCOPE_AGENT) < need)
    __builtin_amdgcn_s_sleep(2);
}

// Light barrier: order LDS writes (lgkmcnt) + store-data reads (expcnt)
// but leave global loads/stores in flight across the barrier (T4: never
// drain vmcnt in the main loop). "memory" clobber pins memory-op order.
__device__ __forceinline__ void light_barrier() {
  asm volatile("s_waitcnt expcnt(0) lgkmcnt(0)" ::: "memory");
  __builtin_amdgcn_s_barrier();
}

// LDS B layout (fp16, K=512 = [inp 256 | h 256]):
//   granule (16B) for (k,n): u = (k>>5)*4 + ((k>>3)&3), v = n, j = k&7
//   half-index = (u*16 + (v ^ (u&7)))*8 + j     (XOR swizzle kills write
//   conflicts; reads at fixed u keep all 16 v' distinct -> conflict-free)
__global__ __launch_bounds__(512, 2)
void stacked_rnn(const float* __restrict__ x,
                 const int* __restrict__ seq_lens,
                 const float* __restrict__ Wih,
                 const float* __restrict__ Whh,
                 const float* __restrict__ bias,
                 float* __restrict__ out,
                 int* flags) {
  const int ks = blockIdx.x;           // depth stage 0..2
  const int tid = (int)threadIdx.x;
  const int w = tid >> 6;              // wave 0..7 -> rows [32w, 32w+32)
  const int lane = tid & 63;
  const int q = lane >> 4;
  const int n = lane & 15;             // batch column

  __shared__ __align__(16) unsigned short Bsm[2][8192];   // 2 x 16KB ping-pong

  int* flag_up = flags + (ks - 1) * 64;
  int* flag_me = flags + ks * 64;

  // ---- persistent weight A-fragments (fp16, RTN): kt<8 = W_ih, kt>=8 = W_hh
  h16x8 wf[2][16];
  {
    const float* wih_s = Wih + ks * (HH * HH);
    const float* whh_s = Whh + ks * (HH * HH);
#pragma unroll
    for (int mti = 0; mti < 2; ++mti) {
      const int fA = w * 32 + mti * 16 + n;      // A row = lane&15
#pragma unroll
      for (int kt = 0; kt < 16; ++kt) {
        const int col = (kt & 7) * 32 + q * 8;   // A k = quad*8 + j
        const float* src = (kt < 8) ? (wih_s + fA * HH + col)
                                    : (whh_s + fA * HH + col);
        float4 a0 = ((const float4*)src)[0];
        float4 a1 = ((const float4*)src)[1];
        h16x8 f;
        f[0] = (_Float16)a0.x; f[1] = (_Float16)a0.y;
        f[2] = (_Float16)a0.z; f[3] = (_Float16)a0.w;
        f[4] = (_Float16)a1.x; f[5] = (_Float16)a1.y;
        f[6] = (_Float16)a1.z; f[7] = (_Float16)a1.w;
        wf[mti][kt] = f;
      }
    }
  }

  // ---- bias in C-layout (row = q*4+r, col = n), exact fp32
  f32x4 biasv[2];
#pragma unroll
  for (int mti = 0; mti < 2; ++mti)
#pragma unroll
    for (int r = 0; r < 4; ++r)
      biasv[mti][r] = bias[ks * HH + w * 32 + mti * 16 + q * 4 + r];

  const int sl = seq_lens[n];

  // ---- fragment read offsets (halves): frag kt at rd{E,O} + kt*512
  const int rdE = (q * 16 + (n ^ q)) * 8;        // even kt: u&7 = q
  const int rdO = (q * 16 + (n ^ q ^ 4)) * 8;    // odd  kt: u&7 = q+4

  // ---- h-repack write offsets (uint2 = 4 halves, j0 = (q&1)*4)
  int hofs[2];
#pragma unroll
  for (int mti = 0; mti < 2; ++mti) {
    const int u = (8 + w) * 4 + mti * 2 + (q >> 1);
    hofs[mti] = (u * 16 + (n ^ (u & 7))) * 8 + (q & 1) * 4;
  }

  // ---- loader: 512 chunks of 8 floats = {n 0..15} x {k8 0..31}, 1/thread
  const int n_l = tid >> 5;
  const int k8  = tid & 31;
  const int u_l = (k8 >> 2) * 4 + (k8 & 3);
  const int ldst = (u_l * 16 + (n_l ^ (u_l & 7))) * 8;

  const float* src_base;
  int src_stride;
  if (ks == 0) {
    src_base = x + ((n_l * TT) << 8) + (k8 << 3);
    src_stride = HH;
  } else {
    src_base = out + (((n_l * TT) * 3 + (ks - 1)) << 8) + (k8 << 3);
    src_stride = 3 * HH;
  }

  // ---- zero h-half of buf0 (h_{-1} = 0): 8KB, one b128 store per thread
  ((uint4*)&Bsm[0][4096])[tid] = make_uint4(0, 0, 0, 0);
  if (ks > 0 && tid == 0) spin_ge(flag_up, 18);   // covers preload + chunk 0
  __syncthreads();

  // ---- preload inp_0 -> buf0, inp_1 -> pfB, pf pointer at t=2
  {
    float4 c0 = ((const float4*)src_base)[0];
    float4 c1 = ((const float4*)src_base)[1];
    *(uint4*)&Bsm[0][ldst] = make_uint4(pkrtz(c0.x, c0.y), pkrtz(c0.z, c0.w),
                                        pkrtz(c1.x, c1.y), pkrtz(c1.z, c1.w));
  }
  float4 pfB0 = ((const float4*)(src_base + src_stride))[0];
  float4 pfB1 = ((const float4*)(src_base + src_stride))[1];
  const float* src_pf = src_base + 2 * src_stride;
  __syncthreads();

  float* outp = out + ((n * TT) * 3 + ks) * HH + w * 32 + q * 4;

  for (int t = 0; t < TT; ++t) {
    unsigned short* Bp = Bsm[t & 1];
    unsigned short* Bq = Bsm[(t & 1) ^ 1];

    // ---- publish (multiples of 8; stores drained by the full barrier at
    //      the end of iter t-1, since (t-1)&7 == 7)
    if ((t & 7) == 0 && t > 0 && ks < 2 && tid == 0)
      __hip_atomic_store(flag_me, t, __ATOMIC_RELEASE,
                         __HIP_MEMORY_SCOPE_AGENT);
    // ---- chunk gate: iters t..t+15 load steps t+2..t+17 -> need flag t+18
    if ((t & 15) == 0 && t > 0 && ks > 0) {
      if (tid == 0) {
        int need = t + 18;
        if (need > TT) need = TT;
        spin_ge(flag_up, need);
      }
      __syncthreads();
    }

    // ---- issue global prefetch for inp_{t+2}
    float4 pfA0, pfA1;
    const bool more2 = (t + 2 < TT);
    if (more2) {
      pfA0 = ((const float4*)src_pf)[0];
      pfA1 = ((const float4*)src_pf)[1];
    }
    src_pf += src_stride;

    // ---- GEMM: acc = bias + Wcat @ [inp_t ; h_{t-1}]
    f32x4 acc[2] = {biasv[0], biasv[1]};
#pragma unroll
    for (int kt = 0; kt < 16; ++kt) {
      const int ofs = ((kt & 1) ? rdO : rdE) + kt * 512;
      h16x8 bf = *(const h16x8*)&Bp[ofs];
      acc[0] = __builtin_amdgcn_mfma_f32_16x16x32_f16(wf[0][kt], bf, acc[0], 0, 0, 0);
      acc[1] = __builtin_amdgcn_mfma_f32_16x16x32_f16(wf[1][kt], bf, acc[1], 0, 0, 0);
    }

    // ---- tanh + masked fp32 output store (h kept unmasked for recurrence)
    const bool live = (t < sl);
    uint2 hpk[2];
#pragma unroll
    for (int mti = 0; mti < 2; ++mti) {
      float h0 = tanh_fast(acc[mti][0]);
      float h1 = tanh_fast(acc[mti][1]);
      float h2 = tanh_fast(acc[mti][2]);
      float h3 = tanh_fast(acc[mti][3]);
      hpk[mti].x = pkrtz(h0, h1);
      hpk[mti].y = pkrtz(h2, h3);
      float4 od;
      od.x = live ? h0 : 0.0f;
      od.y = live ? h1 : 0.0f;
      od.z = live ? h2 : 0.0f;
      od.w = live ? h3 : 0.0f;
      *(float4*)(outp + mti * 16) = od;
    }
    outp += 3 * HH;

    // ---- write buf p^1: inp_{t+1} (from pfB) + h_t (repack)
    if (t + 1 < TT) {
      *(uint4*)&Bq[ldst] = make_uint4(pkrtz(pfB0.x, pfB0.y), pkrtz(pfB0.z, pfB0.w),
                                      pkrtz(pfB1.x, pfB1.y), pkrtz(pfB1.z, pfB1.w));
      *(uint2*)&Bq[hofs[0]] = hpk[0];
      *(uint2*)&Bq[hofs[1]] = hpk[1];
      if (more2) { pfB0 = pfA0; pfB1 = pfA1; }
    }

    // ---- the one per-step barrier: light (no vmcnt drain) except every
    //      8th step, whose full drain backs the next publish. Uniform branch.
    if ((t & 7) == 7) {
      __syncthreads();
    } else {
      light_barrier();
    }
  }

  if (ks < 2 && tid == 0)
    __hip_atomic_store(flag_me, TT, __ATOMIC_RELEASE, __HIP_MEMORY_SCOPE_AGENT);
}

extern "C" void kernel_launch(void* const* d_in, const int* in_sizes, int n_in,
                              void* d_out, int out_size, void* d_ws, size_t ws_size,
                              hipStream_t stream) {
  (void)in_sizes; (void)n_in; (void)out_size; (void)ws_size;
  const float* x   = (const float*)d_in[0];
  const int*   sl  = (const int*)d_in[1];
  const float* wih = (const float*)d_in[2];
  const float* whh = (const float*)d_in[3];
  const float* b   = (const float*)d_in[4];

  // zero the progress flags (ws is poisoned 0xAA before every launch)
  (void)hipMemsetAsync(d_ws, 0, 1024, stream);
  hipLaunchKernelGGL(stacked_rnn, dim3(3), dim3(512), 0, stream,
                     x, sl, wih, whh, b, (float*)d_out, (int*)d_ws);
}